// Round 2
// baseline (431.654 us; speedup 1.0000x reference)
//
#include <hip/hip_runtime.h>
#include <cstdint>
#include <cstddef>

typedef float   f32x4 __attribute__((ext_vector_type(4)));
typedef _Float16 f16x8 __attribute__((ext_vector_type(8)));
typedef _Float16 f16x4 __attribute__((ext_vector_type(4)));

#define TOK  4096   // B*S tokens
#define HID  1024
#define IDIM 4096

// direct global->LDS async copy, 16 B per lane (wave-uniform LDS base + lane*16)
#define GLDS16(gp, lp) __builtin_amdgcn_global_load_lds(                      \
    (const __attribute__((address_space(1))) void*)(gp),                      \
    (__attribute__((address_space(3))) void*)(lp), 16, 0, 0)

// LDS layout (kh-major): 8 KB tile = 512 slots of 16 B. slot = kh*128 + row,
// kh = k-octet (k8 = kh*8), row = tile row. gload_lds writes linearly
// (base + lane*16); fragment ds_read_b128 hits 16 consecutive slots -> no
// bank conflicts (vs 8-way for row-major [128][32]).

// ---------------------------------------------------------------------------
// Dense GEMM: 128x128 tile, BK=32, 256 thr = 4 waves (2x2), wave 64x64
// (4x4 MFMA 16x16x32 f16). Split-K over blockIdx.z. Writes fp32 partials.
// ---------------------------------------------------------------------------
__global__ __launch_bounds__(256, 4) void gemm_dense(
    const _Float16* __restrict__ A, const _Float16* __restrict__ B,
    int K, int Kchunk, float* __restrict__ part)
{
    __shared__ _Float16 lA[4096];
    __shared__ _Float16 lB[4096];
    const int tid  = threadIdx.x;
    const int lane = tid & 63;
    const int wave = tid >> 6;
    const int m0   = blockIdx.x * 128;
    const int n0   = blockIdx.y * 128;
    const int kz0  = blockIdx.z * Kchunk;
    const int wM   = (wave & 1) * 64;
    const int wN   = (wave >> 1) * 64;

    // wave w stages slots [w*128, w*128+128) of each matrix: kh = w,
    // rows lane (first 64 slots) and 64+lane (next 64).
    const _Float16* gA0 = A + (size_t)(m0 + lane) * K + kz0 + wave * 8;
    const _Float16* gA1 = gA0 + (size_t)64 * K;
    const _Float16* gB0 = B + (size_t)(n0 + lane) * K + kz0 + wave * 8;
    const _Float16* gB1 = gB0 + (size_t)64 * K;
    _Float16* sA0 = lA + wave * 1024;
    _Float16* sB0 = lB + wave * 1024;

    f32x4 acc[4][4] = {};
    const int fr  = lane & 15;
    const int khr = lane >> 4;   // which k-octet this lane's fragment needs

    for (int k = 0; k < Kchunk; k += 32) {
        GLDS16(gA0 + k, sA0);
        GLDS16(gA1 + k, sA0 + 512);
        GLDS16(gB0 + k, sB0);
        GLDS16(gB1 + k, sB0 + 512);
        __syncthreads();   // drains vmcnt(0)
        f16x8 afr[4], bfr[4];
#pragma unroll
        for (int mi = 0; mi < 4; ++mi)
            afr[mi] = *(const f16x8*)(lA + (khr * 128 + wM + mi * 16 + fr) * 8);
#pragma unroll
        for (int ni = 0; ni < 4; ++ni)
            bfr[ni] = *(const f16x8*)(lB + (khr * 128 + wN + ni * 16 + fr) * 8);
#pragma unroll
        for (int mi = 0; mi < 4; ++mi)
#pragma unroll
            for (int ni = 0; ni < 4; ++ni)
                acc[mi][ni] = __builtin_amdgcn_mfma_f32_16x16x32_f16(
                    afr[mi], bfr[ni], acc[mi][ni], 0, 0, 0);
        __syncthreads();
    }

    float* dst = part + (size_t)blockIdx.z * TOK * HID;
    const int cn = lane & 15;
    const int rq = (lane >> 4) * 4;
#pragma unroll
    for (int mi = 0; mi < 4; ++mi)
#pragma unroll
        for (int r = 0; r < 4; ++r) {
            const int m = m0 + wM + mi * 16 + rq + r;
#pragma unroll
            for (int ni = 0; ni < 4; ++ni) {
                const int n = n0 + wN + ni * 16 + cn;
                dst[(size_t)m * HID + n] = acc[mi][ni][r];
            }
        }
}

// ---------------------------------------------------------------------------
// Small-K GEMM: 1024 thr = 16 waves (4x4), wave 32x32 (2x2 MFMA), 128x128
// tile, gload_lds staging (1 issue/wave/K-step), kh-major LDS.
// MODE 1: outH = f16(acc + (bias?bias[n]:0))
// MODE 3: outH = f16(acc + addv + sum_t probs*up_b)
// MODE 4: outF = acc + addv
// MODE 5: dual N=512 GEMM: by<4 -> down=relu(Ah@B^T+bias); by>=4 -> g=A2@B2^T
// ---------------------------------------------------------------------------
template <int MODE>
__global__ __launch_bounds__(1024, 4) void gemm_w32(
    const _Float16* __restrict__ Ah, const _Float16* __restrict__ B,
    int K, int Ncols,
    float* __restrict__ outF, _Float16* __restrict__ outH,
    const float* __restrict__ bias, const float* __restrict__ addv,
    const float* __restrict__ probs, const float* __restrict__ upb,
    const _Float16* __restrict__ A2, const _Float16* __restrict__ B2,
    _Float16* __restrict__ outH2)
{
    __shared__ _Float16 lA[4096];
    __shared__ _Float16 lB[4096];
    const int tid  = threadIdx.x;
    const int lane = tid & 63;
    const int wave = tid >> 6;
    const int m0   = blockIdx.x * 128;
    int n0, half = 0;
    const _Float16* Ap = Ah;
    const _Float16* Bp = B;
    if constexpr (MODE == 5) {
        half = blockIdx.y >> 2;
        n0 = (blockIdx.y & 3) * 128;
        if (half) { Ap = A2; Bp = B2; }
    } else {
        n0 = blockIdx.y * 128;
    }
    const int wM = (wave & 3) * 32;
    const int wN = (wave >> 2) * 32;

    f32x4 acc[2][2] = {};

    // waves 0-7 stage A slots [i8*64, i8*64+64), waves 8-15 stage B.
    // slot s = i8*64 + lane: kh = i8>>1, row = (i8&1)*64 + lane.
    const int i8 = wave & 7;
    const _Float16* gsrc = ((wave < 8)
        ? Ap + (size_t)(m0 + (i8 & 1) * 64 + lane) * K
        : Bp + (size_t)(n0 + (i8 & 1) * 64 + lane) * K) + (i8 >> 1) * 8;
    _Float16* ldst = ((wave < 8) ? lA : lB) + i8 * 512;

    const int fr  = lane & 15;
    const int khr = lane >> 4;

    for (int k0 = 0; k0 < K; k0 += 32) {
        GLDS16(gsrc + k0, ldst);
        __syncthreads();
        f16x8 afr[2], bfr[2];
#pragma unroll
        for (int mi = 0; mi < 2; ++mi)
            afr[mi] = *(const f16x8*)(lA + (khr * 128 + wM + mi * 16 + fr) * 8);
#pragma unroll
        for (int ni = 0; ni < 2; ++ni)
            bfr[ni] = *(const f16x8*)(lB + (khr * 128 + wN + ni * 16 + fr) * 8);
#pragma unroll
        for (int mi = 0; mi < 2; ++mi)
#pragma unroll
            for (int ni = 0; ni < 2; ++ni)
                acc[mi][ni] = __builtin_amdgcn_mfma_f32_16x16x32_f16(
                    afr[mi], bfr[ni], acc[mi][ni], 0, 0, 0);
        __syncthreads();
    }

    const int cn = lane & 15;
    const int rq = (lane >> 4) * 4;
#pragma unroll
    for (int mi = 0; mi < 2; ++mi)
#pragma unroll
        for (int r = 0; r < 4; ++r) {
            const int m = m0 + wM + mi * 16 + rq + r;
#pragma unroll
            for (int ni = 0; ni < 2; ++ni) {
                const int n = n0 + wN + ni * 16 + cn;
                const float v = acc[mi][ni][r];
                if constexpr (MODE == 1) {
                    const float bb = bias ? bias[n] : 0.f;
                    outH[(size_t)m * Ncols + n] = (_Float16)(v + bb);
                } else if constexpr (MODE == 3) {
                    const size_t idx = (size_t)m * Ncols + n;
                    float s = v + addv[idx];
#pragma unroll
                    for (int t = 0; t < 8; ++t)
                        s += probs[(size_t)m * 8 + t] * upb[t * 1024 + n];
                    outH[idx] = (_Float16)s;
                } else if constexpr (MODE == 4) {
                    const size_t idx = (size_t)m * Ncols + n;
                    outF[idx] = v + addv[idx];
                } else {  // MODE 5
                    const size_t idx = (size_t)m * 512 + n;
                    if (half == 0) {
                        const float y = v + bias[n];
                        outH[idx] = (_Float16)(y > 0.f ? y : 0.f);
                    } else {
                        outH2[idx] = (_Float16)v;
                    }
                }
            }
        }
}

// ---------------------------------------------------------------------------
// fused split-K reduce + bias + LN: h = sum_z part[z] + dense_b;
// prenorm = h + it; ai = LN(prenorm); emits h_f32, ai(f16), pn(f16)
// ---------------------------------------------------------------------------
__global__ __launch_bounds__(256) void ln_fused(
    const float* __restrict__ part, int sk,
    const float* __restrict__ dbias, const float* __restrict__ it,
    const float* __restrict__ gam, const float* __restrict__ bet,
    float* __restrict__ h_f32, _Float16* __restrict__ ai, _Float16* __restrict__ pn)
{
    const int n = blockIdx.x, tid = threadIdx.x;
    const int lane = tid & 63, wave = tid >> 6;
    const size_t base = (size_t)n * 1024 + tid * 4;
    f32x4 h = *(const f32x4*)(dbias + tid * 4);
    for (int z = 0; z < sk; ++z)
        h += *(const f32x4*)(part + (size_t)z * TOK * HID + base);
    *(f32x4*)(h_f32 + base) = h;
    f32x4 x = h + *(const f32x4*)(it + base);
    float s = x[0] + x[1] + x[2] + x[3];
    float q = x[0] * x[0] + x[1] * x[1] + x[2] * x[2] + x[3] * x[3];
#pragma unroll
    for (int off = 1; off < 64; off <<= 1) {
        s += __shfl_xor(s, off);
        q += __shfl_xor(q, off);
    }
    __shared__ float rs[4], rq[4];
    if (lane == 0) { rs[wave] = s; rq[wave] = q; }
    __syncthreads();
    s = rs[0] + rs[1] + rs[2] + rs[3];
    q = rq[0] + rq[1] + rq[2] + rq[3];
    const float mu = s * (1.f / 1024.f);
    const float var = q * (1.f / 1024.f) - mu * mu;
    const float rstd = rsqrtf(var + 1e-12f);
    f32x4 gv = *(const f32x4*)(gam + tid * 4);
    f32x4 bv = *(const f32x4*)(bet + tid * 4);
    f16x4 av, pv;
#pragma unroll
    for (int j = 0; j < 4; ++j) {
        const float y = (x[j] - mu) * rstd * gv[j] + bv[j];
        av[j] = (_Float16)y;
        pv[j] = (_Float16)x[j];
    }
    *(f16x4*)(ai + base) = av;
    *(f16x4*)(pn + base) = pv;
}

// final LN: out = LN(fuse) where fuse already = input_tensor + fusion
__global__ __launch_bounds__(256) void ln_out(
    const float* __restrict__ fuse, const float* __restrict__ gam,
    const float* __restrict__ bet, float* __restrict__ outp)
{
    const int n = blockIdx.x, tid = threadIdx.x;
    const int lane = tid & 63, wave = tid >> 6;
    const size_t base = (size_t)n * 1024 + tid * 4;
    f32x4 x = *(const f32x4*)(fuse + base);
    float s = x[0] + x[1] + x[2] + x[3];
    float q = x[0] * x[0] + x[1] * x[1] + x[2] * x[2] + x[3] * x[3];
#pragma unroll
    for (int off = 1; off < 64; off <<= 1) {
        s += __shfl_xor(s, off);
        q += __shfl_xor(q, off);
    }
    __shared__ float rs[4], rq[4];
    if (lane == 0) { rs[wave] = s; rq[wave] = q; }
    __syncthreads();
    s = rs[0] + rs[1] + rs[2] + rs[3];
    q = rq[0] + rq[1] + rq[2] + rq[3];
    const float mu = s * (1.f / 1024.f);
    const float var = q * (1.f / 1024.f) - mu * mu;
    const float rstd = rsqrtf(var + 1e-12f);
    f32x4 gv = *(const f32x4*)(gam + tid * 4);
    f32x4 bv = *(const f32x4*)(bet + tid * 4);
    f32x4 y;
#pragma unroll
    for (int j = 0; j < 4; ++j) y[j] = (x[j] - mu) * rstd * gv[j] + bv[j];
    *(f32x4*)(outp + base) = y;
}

// ---------------------------------------------------------------------------
// scores + softmax over T + wdown = probs * down, per token.
// score[t] (up to a t-independent constant that cancels in softmax) =
//   down . g  +  sum_h qk[h]*up_b[t,h]
// ---------------------------------------------------------------------------
__global__ __launch_bounds__(256) void scores_softmax(
    const _Float16* __restrict__ qk, const float* __restrict__ up_b,
    const _Float16* __restrict__ down, const _Float16* __restrict__ g,
    float* __restrict__ probs_out, _Float16* __restrict__ wdown)
{
    const int n = blockIdx.x, tid = threadIdx.x;
    const int lane = tid & 63, wave = tid >> 6;
    const _Float16* qkrow = qk + (size_t)n * 1024;
    float ub[8] = {};
#pragma unroll
    for (int j = 0; j < 4; ++j) {
        const int h = tid + j * 256;
        const float qkv = (float)qkrow[h];
#pragma unroll
        for (int t = 0; t < 8; ++t) ub[t] += qkv * up_b[t * 1024 + h];
    }
#pragma unroll
    for (int off = 1; off < 64; off <<= 1) {
#pragma unroll
        for (int t = 0; t < 8; ++t) ub[t] += __shfl_xor(ub[t], off);
    }
    __shared__ float red[4][9];
    __shared__ float sd[8];
    __shared__ float pl[8];
    if (lane == 0) {
#pragma unroll
        for (int t = 0; t < 8; ++t) red[wave][t] = ub[t];
    }
    const int c0 = tid * 2;
    const size_t dbase = (size_t)n * 512;
    const float d0 = (float)down[dbase + c0];
    const float d1 = (float)down[dbase + c0 + 1];
    float pz = d0 * (float)g[dbase + c0] + d1 * (float)g[dbase + c0 + 1];
#pragma unroll
    for (int off = 1; off < 32; off <<= 1) pz += __shfl_xor(pz, off);
    if ((lane & 31) == 0) sd[wave * 2 + (lane >> 5)] = pz;
    __syncthreads();
    if (tid == 0) {
        float sc[8];
        float mx = -1e30f;
#pragma unroll
        for (int t = 0; t < 8; ++t) {
            sc[t] = sd[t] + red[0][t] + red[1][t] + red[2][t] + red[3][t];
            mx = fmaxf(mx, sc[t]);
        }
        float sum = 0.f;
#pragma unroll
        for (int t = 0; t < 8; ++t) { sc[t] = expf(sc[t] - mx); sum += sc[t]; }
        const float inv = 1.f / sum;
#pragma unroll
        for (int t = 0; t < 8; ++t) pl[t] = sc[t] * inv;
    }
    __syncthreads();
    const float pr = pl[c0 >> 6];
    wdown[dbase + c0]     = (_Float16)(pr * d0);
    wdown[dbase + c0 + 1] = (_Float16)(pr * d1);
    if (tid < 8) probs_out[(size_t)n * 8 + tid] = pl[tid];
}

// ---------------------------------------------------------------------------
// conversions / layout prep
// ---------------------------------------------------------------------------
__device__ inline void cvt_seg(const float* __restrict__ s, _Float16* __restrict__ d,
                               int n4, int gid, int gsz)
{
    for (int i = gid; i < n4; i += gsz) {
        f32x4 v = ((const f32x4*)s)[i];
        f16x4 o;
        o[0] = (_Float16)v[0]; o[1] = (_Float16)v[1];
        o[2] = (_Float16)v[2]; o[3] = (_Float16)v[3];
        ((f16x4*)d)[i] = o;
    }
}

__global__ __launch_bounds__(256) void convert4(
    const float* s0, _Float16* d0, int n0,
    const float* s1, _Float16* d1, int n1,
    const float* s2, _Float16* d2, int n2,
    const float* s3, _Float16* d3, int n3,
    float* bz)   // zero 1024-float accumulator for bfuse
{
    if (blockIdx.x == 0) {
        f32x4 z = {0.f, 0.f, 0.f, 0.f};
        *(f32x4*)(bz + threadIdx.x * 4) = z;
    }
    const int gid = blockIdx.x * 256 + threadIdx.x;
    const int gsz = gridDim.x * 256;
    cvt_seg(s0, d0, n0, gid, gsz);
    cvt_seg(s1, d1, n1, gid, gsz);
    cvt_seg(s2, d2, n2, gid, gsz);
    cvt_seg(s3, d3, n3, gid, gsz);
}

// in [k,h] fp32 -> outp [h,k] f16; optionally rout[h] += sum_k rvec[k]*in[k,h]
__global__ __launch_bounds__(256) void transpose_kw(
    const float* __restrict__ in, _Float16* __restrict__ outp,
    const float* __restrict__ rvec, float* __restrict__ rout)
{
    __shared__ float t[32][33];
    __shared__ float rpart[8][33];
    const int bx = blockIdx.x * 32;   // h
    const int by = blockIdx.y * 32;   // k
    const int tx = threadIdx.x & 31, ty = threadIdx.x >> 5;
#pragma unroll
    for (int j = 0; j < 32; j += 8)
        t[ty + j][tx] = in[(size_t)(by + ty + j) * 1024 + bx + tx];
    __syncthreads();
#pragma unroll
    for (int j = 0; j < 32; j += 8)
        outp[(size_t)(bx + ty + j) * 1024 + by + tx] = (_Float16)t[tx][ty + j];
    if (rvec) {
        float s = 0.f;
#pragma unroll
        for (int j = 0; j < 4; ++j) {
            const int k = ty * 4 + j;
            s += rvec[by + k] * t[k][tx];
        }
        rpart[ty][tx] = s;
        __syncthreads();
        if (ty == 0) {
            float v = rpart[0][tx];
#pragma unroll
            for (int r = 1; r < 8; ++r) v += rpart[r][tx];
            atomicAdd(rout + bx + tx, v);
        }
    }
}

// up_w [t,h,d] -> w_upg[(t*64+d), h]  and  w_upmix[h, t*64+d]   (f16)
__global__ __launch_bounds__(256) void reshape_up(
    const float* __restrict__ up_w, _Float16* __restrict__ upg,
    _Float16* __restrict__ upmix)
{
    const int i = blockIdx.x * 256 + threadIdx.x;
    const int d = i & 63;
    const int h = (i >> 6) & 1023;
    const int t = i >> 16;
    const float v = up_w[i];
    upg[(size_t)(t * 64 + d) * 1024 + h] = (_Float16)v;
    upmix[(size_t)h * 512 + t * 64 + d]  = (_Float16)v;
}

// ---------------------------------------------------------------------------
extern "C" void kernel_launch(void* const* d_in, const int* in_sizes, int n_in,
                              void* d_out, int out_size, void* d_ws, size_t ws_size,
                              hipStream_t stream)
{
    const float* hs      = (const float*)d_in[0];
    const float* it      = (const float*)d_in[1];
    const float* dense_w = (const float*)d_in[2];
    const float* dense_b = (const float*)d_in[3];
    const float* ln_g    = (const float*)d_in[4];
    const float* ln_b    = (const float*)d_in[5];
    const float* down_w  = (const float*)d_in[6];
    const float* down_b  = (const float*)d_in[7];
    const float* up_w    = (const float*)d_in[8];
    const float* up_b    = (const float*)d_in[9];
    const float* key_w   = (const float*)d_in[10];
    const float* key_b   = (const float*)d_in[11];
    const float* query_w = (const float*)d_in[12];
    const float* query_b = (const float*)d_in[13];
    const float* value_w = (const float*)d_in[14];
    float* outp = (float*)d_out;
    (void)in_sizes; (void)n_in; (void)out_size; (void)key_b;

    const size_t MiB = 1ull << 20;
    // persistent region (52 MiB)
    char* p = (char*)d_ws;
    _Float16* w_dense  = (_Float16*)p; p += 8 * MiB;
    _Float16* w_queryT = (_Float16*)p; p += 2 * MiB;   // query_w^T [h,q] f16
    _Float16* w_keyT   = (_Float16*)p; p += 2 * MiB;   // key_w^T [h,k] f16
    _Float16* w_value  = (_Float16*)p; p += 2 * MiB;
    _Float16* w_fuseT  = (_Float16*)p; p += 2 * MiB;   // (Wq^T Wk)^T [h',h] f16
    _Float16* w_down   = (_Float16*)p; p += 1 * MiB;
    _Float16* w_upg    = (_Float16*)p; p += 1 * MiB;
    _Float16* w_upmix  = (_Float16*)p; p += 1 * MiB;
    float*    bfuse    = (float*)p;    p += 1 * MiB;   // qb @ Wk  (1024 f32)
    float*    h_f32    = (float*)p;    p += 16 * MiB;
    _Float16* ai       = (_Float16*)p; p += 8 * MiB;   // reused as `mixed`
    _Float16* pn       = (_Float16*)p; p += 8 * MiB;
    // hs_h (32 MiB) aliases h_f32+ai+pn: dead before ln_fused writes them
    _Float16* hs_h = (_Float16*)h_f32;
    // region B: split-K partials first, then (aliased) activations
    char* rb = p;
    const int sk = (ws_size >= (size_t)(52 + 64) * MiB) ? 4 : 2;
    float*    part  = (float*)rb;                 // sk * 16 MiB
    _Float16* qk    = (_Float16*)(rb +  8 * MiB); // 8 MiB   (part dead by then)
    _Float16* down  = (_Float16*)(rb + 16 * MiB); // 4 MiB
    _Float16* g     = (_Float16*)(rb + 20 * MiB); // 4 MiB
    _Float16* wdown = (_Float16*)(rb + 24 * MiB); // 4 MiB
    float*    probs = (float*)(rb + 28 * MiB);    // 128 KiB
    float*    fuse  = (float*)rb;                 // 16 MiB, aliases qk (dead)
    _Float16* mixed = ai;

    // weight prep + hs fp32->f16; zero bfuse (block 0)
    convert4<<<2048, 256, 0, stream>>>(hs, hs_h, TOK * IDIM / 4,
                                       dense_w, w_dense, HID * IDIM / 4,
                                       value_w, w_value, HID * HID / 4,
                                       down_w,  w_down,  512 * HID / 4,
                                       bfuse);
    // w_keyT = key_w^T, and bfuse[h'] = sum_k query_b[k]*key_w[k,h']
    transpose_kw<<<dim3(32, 32), 256, 0, stream>>>(key_w, w_keyT, query_b, bfuse);
    transpose_kw<<<dim3(32, 32), 256, 0, stream>>>(query_w, w_queryT, nullptr, nullptr);
    reshape_up<<<2048, 256, 0, stream>>>(up_w, w_upg, w_upmix);
    // w_fuseT[h',h] = sum_q key_w[q,h'] * query_w[q,h]   (weight-only GEMM)
    gemm_w32<1><<<dim3(8, 8), 1024, 0, stream>>>(
        w_keyT, w_queryT, HID, HID, nullptr, w_fuseT, nullptr, nullptr, nullptr,
        nullptr, nullptr, nullptr, nullptr);

    // dense partials: part[z] = hs_h @ dense_w^T  (K chunk per z)
    gemm_dense<<<dim3(32, 8, sk), 256, 0, stream>>>(hs_h, w_dense, IDIM, IDIM / sk, part);
    // h = sum partials + dense_b; ai = LN(h + it); pn = f16(h + it)
    ln_fused<<<TOK, 256, 0, stream>>>(part, sk, dense_b, it, ln_g, ln_b, h_f32, ai, pn);
    // qk = pn @ w_fuseT^T + bfuse   (== (pn@Wq^T + qb) @ Wk)
    gemm_w32<1><<<dim3(32, 8), 1024, 0, stream>>>(
        pn, w_fuseT, HID, HID, nullptr, qk, bfuse, nullptr, nullptr, nullptr,
        nullptr, nullptr, nullptr);
    // dual: down = relu(ai @ w_down^T + down_b);  g = qk @ w_upg^T
    gemm_w32<5><<<dim3(32, 8), 1024, 0, stream>>>(
        ai, w_down, HID, 512, nullptr, down, down_b, nullptr, nullptr, nullptr,
        qk, w_upg, g);
    // scores -> softmax over T -> probs, wdown = probs*down
    scores_softmax<<<TOK, 256, 0, stream>>>(qk, up_b, down, g, probs, wdown);
    // mixed = wdown @ up_w^T + probs@up_b + h
    gemm_w32<3><<<dim3(32, 8), 1024, 0, stream>>>(
        wdown, w_upmix, 512, HID, nullptr, mixed, nullptr, h_f32, probs, up_b,
        nullptr, nullptr, nullptr);
    // fuse = mixed @ value_w^T + input_tensor
    gemm_w32<4><<<dim3(32, 8), 1024, 0, stream>>>(
        mixed, w_value, HID, HID, fuse, nullptr, nullptr, it, nullptr, nullptr,
        nullptr, nullptr, nullptr);
    // out = LN(fuse)
    ln_out<<<TOK, 256, 0, stream>>>(fuse, ln_g, ln_b, outp);
}

// Round 3
// 362.749 us; speedup vs baseline: 1.1900x; 1.1900x over previous
//
#include <hip/hip_runtime.h>
#include <cstdint>
#include <cstddef>

typedef float   f32x4 __attribute__((ext_vector_type(4)));
typedef _Float16 f16x8 __attribute__((ext_vector_type(8)));
typedef _Float16 f16x4 __attribute__((ext_vector_type(4)));

#define TOK  4096   // B*S tokens
#define HID  1024
#define IDIM 4096

// direct global->LDS async copy, 16 B per lane (wave-uniform LDS base + lane*16)
#define GLDS16(gp, lp) __builtin_amdgcn_global_load_lds(                      \
    (const __attribute__((address_space(1))) void*)(gp),                      \
    (__attribute__((address_space(3))) void*)(lp), 16, 0, 0)

// LDS tile layout: 512 slots of 16 B; slot(row,kh) = row*4 + (kh ^ ((row>>1)&3)),
// kh = k-octet (16 B) 0..3. Write side: gload_lds lane l stages row base+(l>>2),
// kh = (l&3)^((l>>3)&3)  -> global reads stay 64B-coalesced per 4 lanes AND the
// ds_read_b128 fragment reads are 2-way-per-bank (free) instead of 8-way.
// (both-sides-or-neither swizzle rule: source perm == read perm.)

// ---------------------------------------------------------------------------
// Dense GEMM: 128x128 tile, BK=32, 256 thr = 4 waves (2x2), wave 64x64
// (4x4 MFMA 16x16x32 f16). Split-K over blockIdx.z. Writes fp32 partials.
// ---------------------------------------------------------------------------
__global__ __launch_bounds__(256, 4) void gemm_dense(
    const _Float16* __restrict__ A, const _Float16* __restrict__ B,
    int K, int Kchunk, float* __restrict__ part)
{
    __shared__ _Float16 lA[4096];
    __shared__ _Float16 lB[4096];
    const int tid  = threadIdx.x;
    const int lane = tid & 63;
    const int wave = tid >> 6;
    const int m0   = blockIdx.x * 128;
    const int n0   = blockIdx.y * 128;
    const int kz0  = blockIdx.z * Kchunk;
    const int wM   = (wave & 1) * 64;
    const int wN   = (wave >> 1) * 64;

    // wave w stages rows 32w..32w+15 (issue 0) and 32w+16..32w+31 (issue 1)
    const int srow = lane >> 2;
    const int scol = ((lane & 3) ^ ((lane >> 3) & 3)) * 8;   // swizzled kh
    const _Float16* gA0 = A + (size_t)(m0 + wave * 32 + srow) * K + kz0 + scol;
    const _Float16* gA1 = gA0 + (size_t)16 * K;
    const _Float16* gB0 = B + (size_t)(n0 + wave * 32 + srow) * K + kz0 + scol;
    const _Float16* gB1 = gB0 + (size_t)16 * K;
    _Float16* sA0 = lA + wave * 1024;   // slot base = 128w -> 1024w halfs
    _Float16* sB0 = lB + wave * 1024;

    f32x4 acc[4][4] = {};
    const int fr  = lane & 15;
    const int khr = lane >> 4;
    const int kxo = (khr ^ ((fr >> 1) & 3)) * 8;   // swizzled k-octet (halfs)

    for (int k = 0; k < Kchunk; k += 32) {
        GLDS16(gA0 + k, sA0);
        GLDS16(gA1 + k, sA0 + 512);
        GLDS16(gB0 + k, sB0);
        GLDS16(gB1 + k, sB0 + 512);
        __syncthreads();   // drains vmcnt(0)
        f16x8 afr[4], bfr[4];
#pragma unroll
        for (int mi = 0; mi < 4; ++mi)
            afr[mi] = *(const f16x8*)(lA + (wM + mi * 16 + fr) * 32 + kxo);
#pragma unroll
        for (int ni = 0; ni < 4; ++ni)
            bfr[ni] = *(const f16x8*)(lB + (wN + ni * 16 + fr) * 32 + kxo);
#pragma unroll
        for (int mi = 0; mi < 4; ++mi)
#pragma unroll
            for (int ni = 0; ni < 4; ++ni)
                acc[mi][ni] = __builtin_amdgcn_mfma_f32_16x16x32_f16(
                    afr[mi], bfr[ni], acc[mi][ni], 0, 0, 0);
        __syncthreads();
    }

    float* dst = part + (size_t)blockIdx.z * TOK * HID;
    const int cn = lane & 15;
    const int rq = (lane >> 4) * 4;
#pragma unroll
    for (int mi = 0; mi < 4; ++mi)
#pragma unroll
        for (int r = 0; r < 4; ++r) {
            const int m = m0 + wM + mi * 16 + rq + r;
#pragma unroll
            for (int ni = 0; ni < 4; ++ni) {
                const int n = n0 + wN + ni * 16 + cn;
                dst[(size_t)m * HID + n] = acc[mi][ni][r];
            }
        }
}

// ---------------------------------------------------------------------------
// Small-K GEMM: 1024 thr = 16 waves (4x4), wave 32x32 (2x2 MFMA), 128x128
// tile, gload_lds staging (1 issue/wave/K-step), swizzled-slot LDS.
// MODE 1: outH = f16(acc + (bias?bias[n]:0))
// MODE 3: outH = f16(acc + addv + sum_t probs*up_b)
// MODE 4: outF = acc + addv
// MODE 5: dual N=512 GEMM: by<4 -> down=relu(Ah@B^T+bias); by>=4 -> g=A2@B2^T
// ---------------------------------------------------------------------------
template <int MODE>
__global__ __launch_bounds__(1024, 4) void gemm_w32(
    const _Float16* __restrict__ Ah, const _Float16* __restrict__ B,
    int K, int Ncols,
    float* __restrict__ outF, _Float16* __restrict__ outH,
    const float* __restrict__ bias, const float* __restrict__ addv,
    const float* __restrict__ probs, const float* __restrict__ upb,
    const _Float16* __restrict__ A2, const _Float16* __restrict__ B2,
    _Float16* __restrict__ outH2)
{
    __shared__ _Float16 lA[4096];
    __shared__ _Float16 lB[4096];
    const int tid  = threadIdx.x;
    const int lane = tid & 63;
    const int wave = tid >> 6;
    const int m0   = blockIdx.x * 128;
    int n0, half = 0;
    const _Float16* Ap = Ah;
    const _Float16* Bp = B;
    if constexpr (MODE == 5) {
        half = blockIdx.y >> 2;
        n0 = (blockIdx.y & 3) * 128;
        if (half) { Ap = A2; Bp = B2; }
    } else {
        n0 = blockIdx.y * 128;
    }
    const int wM = (wave & 3) * 32;
    const int wN = (wave >> 2) * 32;

    f32x4 acc[2][2] = {};

    // waves 0-7 stage A rows 16*i8..16*i8+15; waves 8-15 same for B.
    const int i8   = wave & 7;
    const int srow = lane >> 2;
    const int scol = ((lane & 3) ^ ((lane >> 3) & 3)) * 8;
    const _Float16* gsrc = ((wave < 8)
        ? Ap + (size_t)(m0 + i8 * 16 + srow) * K
        : Bp + (size_t)(n0 + i8 * 16 + srow) * K) + scol;
    _Float16* ldst = ((wave < 8) ? lA : lB) + i8 * 512;

    const int fr  = lane & 15;
    const int khr = lane >> 4;
    const int kxo = (khr ^ ((fr >> 1) & 3)) * 8;

    for (int k0 = 0; k0 < K; k0 += 32) {
        GLDS16(gsrc + k0, ldst);
        __syncthreads();
        f16x8 afr[2], bfr[2];
#pragma unroll
        for (int mi = 0; mi < 2; ++mi)
            afr[mi] = *(const f16x8*)(lA + (wM + mi * 16 + fr) * 32 + kxo);
#pragma unroll
        for (int ni = 0; ni < 2; ++ni)
            bfr[ni] = *(const f16x8*)(lB + (wN + ni * 16 + fr) * 32 + kxo);
#pragma unroll
        for (int mi = 0; mi < 2; ++mi)
#pragma unroll
            for (int ni = 0; ni < 2; ++ni)
                acc[mi][ni] = __builtin_amdgcn_mfma_f32_16x16x32_f16(
                    afr[mi], bfr[ni], acc[mi][ni], 0, 0, 0);
        __syncthreads();
    }

    const int cn = lane & 15;
    const int rq = (lane >> 4) * 4;
#pragma unroll
    for (int mi = 0; mi < 2; ++mi)
#pragma unroll
        for (int r = 0; r < 4; ++r) {
            const int m = m0 + wM + mi * 16 + rq + r;
#pragma unroll
            for (int ni = 0; ni < 2; ++ni) {
                const int n = n0 + wN + ni * 16 + cn;
                const float v = acc[mi][ni][r];
                if constexpr (MODE == 1) {
                    const float bb = bias ? bias[n] : 0.f;
                    outH[(size_t)m * Ncols + n] = (_Float16)(v + bb);
                } else if constexpr (MODE == 3) {
                    const size_t idx = (size_t)m * Ncols + n;
                    float s = v + addv[idx];
#pragma unroll
                    for (int t = 0; t < 8; ++t)
                        s += probs[(size_t)m * 8 + t] * upb[t * 1024 + n];
                    outH[idx] = (_Float16)s;
                } else if constexpr (MODE == 4) {
                    const size_t idx = (size_t)m * Ncols + n;
                    outF[idx] = v + addv[idx];
                } else {  // MODE 5
                    const size_t idx = (size_t)m * 512 + n;
                    if (half == 0) {
                        const float y = v + bias[n];
                        outH[idx] = (_Float16)(y > 0.f ? y : 0.f);
                    } else {
                        outH2[idx] = (_Float16)v;
                    }
                }
            }
        }
}

// ---------------------------------------------------------------------------
// fused split-K reduce + bias + LN: h = sum_z part[z] + dense_b;
// prenorm = h + it; ai = LN(prenorm); emits h_f32, ai(f16), pn(f16)
// ---------------------------------------------------------------------------
__global__ __launch_bounds__(256) void ln_fused(
    const float* __restrict__ part, int sk,
    const float* __restrict__ dbias, const float* __restrict__ it,
    const float* __restrict__ gam, const float* __restrict__ bet,
    float* __restrict__ h_f32, _Float16* __restrict__ ai, _Float16* __restrict__ pn)
{
    const int n = blockIdx.x, tid = threadIdx.x;
    const int lane = tid & 63, wave = tid >> 6;
    const size_t base = (size_t)n * 1024 + tid * 4;
    f32x4 h = *(const f32x4*)(dbias + tid * 4);
    for (int z = 0; z < sk; ++z)
        h += *(const f32x4*)(part + (size_t)z * TOK * HID + base);
    *(f32x4*)(h_f32 + base) = h;
    f32x4 x = h + *(const f32x4*)(it + base);
    float s = x[0] + x[1] + x[2] + x[3];
    float q = x[0] * x[0] + x[1] * x[1] + x[2] * x[2] + x[3] * x[3];
#pragma unroll
    for (int off = 1; off < 64; off <<= 1) {
        s += __shfl_xor(s, off);
        q += __shfl_xor(q, off);
    }
    __shared__ float rs[4], rq[4];
    if (lane == 0) { rs[wave] = s; rq[wave] = q; }
    __syncthreads();
    s = rs[0] + rs[1] + rs[2] + rs[3];
    q = rq[0] + rq[1] + rq[2] + rq[3];
    const float mu = s * (1.f / 1024.f);
    const float var = q * (1.f / 1024.f) - mu * mu;
    const float rstd = rsqrtf(var + 1e-12f);
    f32x4 gv = *(const f32x4*)(gam + tid * 4);
    f32x4 bv = *(const f32x4*)(bet + tid * 4);
    f16x4 av, pv;
#pragma unroll
    for (int j = 0; j < 4; ++j) {
        const float y = (x[j] - mu) * rstd * gv[j] + bv[j];
        av[j] = (_Float16)y;
        pv[j] = (_Float16)x[j];
    }
    *(f16x4*)(ai + base) = av;
    *(f16x4*)(pn + base) = pv;
}

// final LN: out = LN(fuse) where fuse already = input_tensor + fusion
__global__ __launch_bounds__(256) void ln_out(
    const float* __restrict__ fuse, const float* __restrict__ gam,
    const float* __restrict__ bet, float* __restrict__ outp)
{
    const int n = blockIdx.x, tid = threadIdx.x;
    const int lane = tid & 63, wave = tid >> 6;
    const size_t base = (size_t)n * 1024 + tid * 4;
    f32x4 x = *(const f32x4*)(fuse + base);
    float s = x[0] + x[1] + x[2] + x[3];
    float q = x[0] * x[0] + x[1] * x[1] + x[2] * x[2] + x[3] * x[3];
#pragma unroll
    for (int off = 1; off < 64; off <<= 1) {
        s += __shfl_xor(s, off);
        q += __shfl_xor(q, off);
    }
    __shared__ float rs[4], rq[4];
    if (lane == 0) { rs[wave] = s; rq[wave] = q; }
    __syncthreads();
    s = rs[0] + rs[1] + rs[2] + rs[3];
    q = rq[0] + rq[1] + rq[2] + rq[3];
    const float mu = s * (1.f / 1024.f);
    const float var = q * (1.f / 1024.f) - mu * mu;
    const float rstd = rsqrtf(var + 1e-12f);
    f32x4 gv = *(const f32x4*)(gam + tid * 4);
    f32x4 bv = *(const f32x4*)(bet + tid * 4);
    f32x4 y;
#pragma unroll
    for (int j = 0; j < 4; ++j) y[j] = (x[j] - mu) * rstd * gv[j] + bv[j];
    *(f32x4*)(outp + base) = y;
}

// ---------------------------------------------------------------------------
// scores + softmax over T + wdown = probs * down, per token.
// score[t] (up to a t-independent constant that cancels in softmax) =
//   down . g  +  sum_h qk[h]*up_b[t,h]
// ---------------------------------------------------------------------------
__global__ __launch_bounds__(256) void scores_softmax(
    const _Float16* __restrict__ qk, const float* __restrict__ up_b,
    const _Float16* __restrict__ down, const _Float16* __restrict__ g,
    float* __restrict__ probs_out, _Float16* __restrict__ wdown)
{
    const int n = blockIdx.x, tid = threadIdx.x;
    const int lane = tid & 63, wave = tid >> 6;
    const _Float16* qkrow = qk + (size_t)n * 1024;
    float ub[8] = {};
#pragma unroll
    for (int j = 0; j < 4; ++j) {
        const int h = tid + j * 256;
        const float qkv = (float)qkrow[h];
#pragma unroll
        for (int t = 0; t < 8; ++t) ub[t] += qkv * up_b[t * 1024 + h];
    }
#pragma unroll
    for (int off = 1; off < 64; off <<= 1) {
#pragma unroll
        for (int t = 0; t < 8; ++t) ub[t] += __shfl_xor(ub[t], off);
    }
    __shared__ float red[4][9];
    __shared__ float sd[8];
    __shared__ float pl[8];
    if (lane == 0) {
#pragma unroll
        for (int t = 0; t < 8; ++t) red[wave][t] = ub[t];
    }
    const int c0 = tid * 2;
    const size_t dbase = (size_t)n * 512;
    const float d0 = (float)down[dbase + c0];
    const float d1 = (float)down[dbase + c0 + 1];
    float pz = d0 * (float)g[dbase + c0] + d1 * (float)g[dbase + c0 + 1];
#pragma unroll
    for (int off = 1; off < 32; off <<= 1) pz += __shfl_xor(pz, off);
    if ((lane & 31) == 0) sd[wave * 2 + (lane >> 5)] = pz;
    __syncthreads();
    if (tid == 0) {
        float sc[8];
        float mx = -1e30f;
#pragma unroll
        for (int t = 0; t < 8; ++t) {
            sc[t] = sd[t] + red[0][t] + red[1][t] + red[2][t] + red[3][t];
            mx = fmaxf(mx, sc[t]);
        }
        float sum = 0.f;
#pragma unroll
        for (int t = 0; t < 8; ++t) { sc[t] = expf(sc[t] - mx); sum += sc[t]; }
        const float inv = 1.f / sum;
#pragma unroll
        for (int t = 0; t < 8; ++t) pl[t] = sc[t] * inv;
    }
    __syncthreads();
    const float pr = pl[c0 >> 6];
    wdown[dbase + c0]     = (_Float16)(pr * d0);
    wdown[dbase + c0 + 1] = (_Float16)(pr * d1);
    if (tid < 8) probs_out[(size_t)n * 8 + tid] = pl[tid];
}

// ---------------------------------------------------------------------------
// conversions / layout prep
// ---------------------------------------------------------------------------
__device__ inline void cvt_seg(const float* __restrict__ s, _Float16* __restrict__ d,
                               int n4, int gid, int gsz)
{
    for (int i = gid; i < n4; i += gsz) {
        f32x4 v = ((const f32x4*)s)[i];
        f16x4 o;
        o[0] = (_Float16)v[0]; o[1] = (_Float16)v[1];
        o[2] = (_Float16)v[2]; o[3] = (_Float16)v[3];
        ((f16x4*)d)[i] = o;
    }
}

__global__ __launch_bounds__(256) void convert4(
    const float* s0, _Float16* d0, int n0,
    const float* s1, _Float16* d1, int n1,
    const float* s2, _Float16* d2, int n2,
    const float* s3, _Float16* d3, int n3,
    float* bz)   // zero 1024-float accumulator for bfuse
{
    if (blockIdx.x == 0) {
        f32x4 z = {0.f, 0.f, 0.f, 0.f};
        *(f32x4*)(bz + threadIdx.x * 4) = z;
    }
    const int gid = blockIdx.x * 256 + threadIdx.x;
    const int gsz = gridDim.x * 256;
    cvt_seg(s0, d0, n0, gid, gsz);
    cvt_seg(s1, d1, n1, gid, gsz);
    cvt_seg(s2, d2, n2, gid, gsz);
    cvt_seg(s3, d3, n3, gid, gsz);
}

// in [k,h] fp32 -> outp [h,k] f16; optionally rout[h] += sum_k rvec[k]*in[k,h]
__global__ __launch_bounds__(256) void transpose_kw(
    const float* __restrict__ in, _Float16* __restrict__ outp,
    const float* __restrict__ rvec, float* __restrict__ rout)
{
    __shared__ float t[32][33];
    __shared__ float rpart[8][33];
    const int bx = blockIdx.x * 32;   // h
    const int by = blockIdx.y * 32;   // k
    const int tx = threadIdx.x & 31, ty = threadIdx.x >> 5;
#pragma unroll
    for (int j = 0; j < 32; j += 8)
        t[ty + j][tx] = in[(size_t)(by + ty + j) * 1024 + bx + tx];
    __syncthreads();
#pragma unroll
    for (int j = 0; j < 32; j += 8)
        outp[(size_t)(bx + ty + j) * 1024 + by + tx] = (_Float16)t[tx][ty + j];
    if (rvec) {
        float s = 0.f;
#pragma unroll
        for (int j = 0; j < 4; ++j) {
            const int k = ty * 4 + j;
            s += rvec[by + k] * t[k][tx];
        }
        rpart[ty][tx] = s;
        __syncthreads();
        if (ty == 0) {
            float v = rpart[0][tx];
#pragma unroll
            for (int r = 1; r < 8; ++r) v += rpart[r][tx];
            atomicAdd(rout + bx + tx, v);
        }
    }
}

// up_w [t,h,d] -> w_upg[(t*64+d), h]  and  w_upmix[h, t*64+d]   (f16)
__global__ __launch_bounds__(256) void reshape_up(
    const float* __restrict__ up_w, _Float16* __restrict__ upg,
    _Float16* __restrict__ upmix)
{
    const int i = blockIdx.x * 256 + threadIdx.x;
    const int d = i & 63;
    const int h = (i >> 6) & 1023;
    const int t = i >> 16;
    const float v = up_w[i];
    upg[(size_t)(t * 64 + d) * 1024 + h] = (_Float16)v;
    upmix[(size_t)h * 512 + t * 64 + d]  = (_Float16)v;
}

// ---------------------------------------------------------------------------
extern "C" void kernel_launch(void* const* d_in, const int* in_sizes, int n_in,
                              void* d_out, int out_size, void* d_ws, size_t ws_size,
                              hipStream_t stream)
{
    const float* hs      = (const float*)d_in[0];
    const float* it      = (const float*)d_in[1];
    const float* dense_w = (const float*)d_in[2];
    const float* dense_b = (const float*)d_in[3];
    const float* ln_g    = (const float*)d_in[4];
    const float* ln_b    = (const float*)d_in[5];
    const float* down_w  = (const float*)d_in[6];
    const float* down_b  = (const float*)d_in[7];
    const float* up_w    = (const float*)d_in[8];
    const float* up_b    = (const float*)d_in[9];
    const float* key_w   = (const float*)d_in[10];
    const float* key_b   = (const float*)d_in[11];
    const float* query_w = (const float*)d_in[12];
    const float* query_b = (const float*)d_in[13];
    const float* value_w = (const float*)d_in[14];
    float* outp = (float*)d_out;
    (void)in_sizes; (void)n_in; (void)out_size; (void)key_b;

    const size_t MiB = 1ull << 20;
    // persistent region (52 MiB)
    char* p = (char*)d_ws;
    _Float16* w_dense  = (_Float16*)p; p += 8 * MiB;
    _Float16* w_queryT = (_Float16*)p; p += 2 * MiB;   // query_w^T [h,q] f16
    _Float16* w_keyT   = (_Float16*)p; p += 2 * MiB;   // key_w^T [h,k] f16
    _Float16* w_value  = (_Float16*)p; p += 2 * MiB;
    _Float16* w_fuseT  = (_Float16*)p; p += 2 * MiB;   // (Wq^T Wk)^T [h',h] f16
    _Float16* w_down   = (_Float16*)p; p += 1 * MiB;
    _Float16* w_upg    = (_Float16*)p; p += 1 * MiB;
    _Float16* w_upmix  = (_Float16*)p; p += 1 * MiB;
    float*    bfuse    = (float*)p;    p += 1 * MiB;   // qb @ Wk  (1024 f32)
    float*    h_f32    = (float*)p;    p += 16 * MiB;
    _Float16* ai       = (_Float16*)p; p += 8 * MiB;   // reused as `mixed`
    _Float16* pn       = (_Float16*)p; p += 8 * MiB;
    // hs_h (32 MiB) aliases h_f32+ai+pn: dead before ln_fused writes them
    _Float16* hs_h = (_Float16*)h_f32;
    // region B: split-K partials first, then (aliased) activations
    char* rb = p;
    const int sk = (ws_size >= (size_t)(52 + 64) * MiB) ? 4 : 2;
    float*    part  = (float*)rb;                 // sk * 16 MiB
    _Float16* qk    = (_Float16*)(rb +  8 * MiB); // 8 MiB   (part dead by then)
    _Float16* down  = (_Float16*)(rb + 16 * MiB); // 4 MiB
    _Float16* g     = (_Float16*)(rb + 20 * MiB); // 4 MiB
    _Float16* wdown = (_Float16*)(rb + 24 * MiB); // 4 MiB
    float*    probs = (float*)(rb + 28 * MiB);    // 128 KiB
    float*    fuse  = (float*)rb;                 // 16 MiB, aliases qk (dead)
    _Float16* mixed = ai;

    // weight prep + hs fp32->f16; zero bfuse (block 0)
    convert4<<<2048, 256, 0, stream>>>(hs, hs_h, TOK * IDIM / 4,
                                       dense_w, w_dense, HID * IDIM / 4,
                                       value_w, w_value, HID * HID / 4,
                                       down_w,  w_down,  512 * HID / 4,
                                       bfuse);
    // w_keyT = key_w^T, and bfuse[h'] = sum_k query_b[k]*key_w[k,h']
    transpose_kw<<<dim3(32, 32), 256, 0, stream>>>(key_w, w_keyT, query_b, bfuse);
    transpose_kw<<<dim3(32, 32), 256, 0, stream>>>(query_w, w_queryT, nullptr, nullptr);
    reshape_up<<<2048, 256, 0, stream>>>(up_w, w_upg, w_upmix);
    // w_fuseT[h',h] = sum_q key_w[q,h'] * query_w[q,h]   (weight-only GEMM)
    gemm_w32<1><<<dim3(8, 8), 1024, 0, stream>>>(
        w_keyT, w_queryT, HID, HID, nullptr, w_fuseT, nullptr, nullptr, nullptr,
        nullptr, nullptr, nullptr, nullptr);

    // dense partials: part[z] = hs_h @ dense_w^T  (K chunk per z)
    gemm_dense<<<dim3(32, 8, sk), 256, 0, stream>>>(hs_h, w_dense, IDIM, IDIM / sk, part);
    // h = sum partials + dense_b; ai = LN(h + it); pn = f16(h + it)
    ln_fused<<<TOK, 256, 0, stream>>>(part, sk, dense_b, it, ln_g, ln_b, h_f32, ai, pn);
    // qk = pn @ w_fuseT^T + bfuse   (== (pn@Wq^T + qb) @ Wk)
    gemm_w32<1><<<dim3(32, 8), 1024, 0, stream>>>(
        pn, w_fuseT, HID, HID, nullptr, qk, bfuse, nullptr, nullptr, nullptr,
        nullptr, nullptr, nullptr);
    // dual: down = relu(ai @ w_down^T + down_b);  g = qk @ w_upg^T
    gemm_w32<5><<<dim3(32, 8), 1024, 0, stream>>>(
        ai, w_down, HID, 512, nullptr, down, down_b, nullptr, nullptr, nullptr,
        qk, w_upg, g);
    // scores -> softmax over T -> probs, wdown = probs*down
    scores_softmax<<<TOK, 256, 0, stream>>>(qk, up_b, down, g, probs, wdown);
    // mixed = wdown @ up_w^T + probs@up_b + h
    gemm_w32<3><<<dim3(32, 8), 1024, 0, stream>>>(
        wdown, w_upmix, 512, HID, nullptr, mixed, nullptr, h_f32, probs, up_b,
        nullptr, nullptr, nullptr);
    // fuse = mixed @ value_w^T + input_tensor
    gemm_w32<4><<<dim3(32, 8), 1024, 0, stream>>>(
        mixed, w_value, HID, HID, fuse, nullptr, nullptr, it, nullptr, nullptr,
        nullptr, nullptr, nullptr);
    // out = LN(fuse)
    ln_out<<<TOK, 256, 0, stream>>>(fuse, ln_g, ln_b, outp);
}

// Round 4
// 345.210 us; speedup vs baseline: 1.2504x; 1.0508x over previous
//
#include <hip/hip_runtime.h>
#include <cstdint>
#include <cstddef>

typedef float   f32x4 __attribute__((ext_vector_type(4)));
typedef _Float16 f16x8 __attribute__((ext_vector_type(8)));
typedef _Float16 f16x4 __attribute__((ext_vector_type(4)));

#define TOK  4096   // B*S tokens
#define HID  1024
#define IDIM 4096

// direct global->LDS async copy, 16 B per lane (wave-uniform LDS base + lane*16)
#define GLDS16(gp, lp) __builtin_amdgcn_global_load_lds(                      \
    (const __attribute__((address_space(1))) void*)(gp),                      \
    (__attribute__((address_space(3))) void*)(lp), 16, 0, 0)

// LDS tile layout: 512 slots of 16 B; slot(row,kh) = row*4 + (kh ^ ((row>>1)&3)),
// kh = k-octet (16 B) 0..3. Write side: gload_lds lane l stages row base+(l>>2),
// kh = (l&3)^((l>>3)&3)  -> global reads stay 64B-coalesced per 4 lanes AND the
// ds_read_b128 fragment reads are 2-way-per-bank (free) instead of 8-way.
// (both-sides-or-neither swizzle rule: source perm == read perm.)
//
// K-loop: minimum 2-phase pipeline (T3): issue STAGE(t+1) BEFORE the
// ds_read+MFMA of tile t; single __syncthreads() per tile (its vmcnt(0)
// drain lands after a full compute phase of overlap instead of immediately
// after issue).

// ---------------------------------------------------------------------------
// Dense GEMM: 128x128 tile, BK=32, 256 thr = 4 waves (2x2), wave 64x64
// (4x4 MFMA 16x16x32 f16). Split-K over blockIdx.z. Writes fp32 partials.
// ---------------------------------------------------------------------------
__global__ __launch_bounds__(256, 4) void gemm_dense(
    const _Float16* __restrict__ A, const _Float16* __restrict__ B,
    int K, int Kchunk, float* __restrict__ part)
{
    __shared__ _Float16 lA[2][4096];
    __shared__ _Float16 lB[2][4096];
    const int tid  = threadIdx.x;
    const int lane = tid & 63;
    const int wave = tid >> 6;
    const int m0   = blockIdx.x * 128;
    const int n0   = blockIdx.y * 128;
    const int kz0  = blockIdx.z * Kchunk;
    const int wM   = (wave & 1) * 64;
    const int wN   = (wave >> 1) * 64;

    // wave w stages rows 32w..32w+15 (issue 0) and 32w+16..32w+31 (issue 1)
    const int srow = lane >> 2;
    const int scol = ((lane & 3) ^ ((lane >> 3) & 3)) * 8;   // swizzled kh
    const _Float16* gA0 = A + (size_t)(m0 + wave * 32 + srow) * K + kz0 + scol;
    const _Float16* gA1 = gA0 + (size_t)16 * K;
    const _Float16* gB0 = B + (size_t)(n0 + wave * 32 + srow) * K + kz0 + scol;
    const _Float16* gB1 = gB0 + (size_t)16 * K;
    const int soff = wave * 1024;   // slot base = 128w -> 1024w halfs

    f32x4 acc[4][4] = {};
    const int fr  = lane & 15;
    const int khr = lane >> 4;
    const int kxo = (khr ^ ((fr >> 1) & 3)) * 8;   // swizzled k-octet (halfs)

    // prologue: stage tile 0 into buf 0
    GLDS16(gA0, &lA[0][soff]);
    GLDS16(gA1, &lA[0][soff + 512]);
    GLDS16(gB0, &lB[0][soff]);
    GLDS16(gB1, &lB[0][soff + 512]);
    __syncthreads();

    int cur = 0;
    for (int k = 0; k < Kchunk; k += 32) {
        if (k + 32 < Kchunk) {          // issue next-tile loads FIRST (overlap)
            const int nb = cur ^ 1;
            GLDS16(gA0 + k + 32, &lA[nb][soff]);
            GLDS16(gA1 + k + 32, &lA[nb][soff + 512]);
            GLDS16(gB0 + k + 32, &lB[nb][soff]);
            GLDS16(gB1 + k + 32, &lB[nb][soff + 512]);
        }
        f16x8 afr[4], bfr[4];
#pragma unroll
        for (int mi = 0; mi < 4; ++mi)
            afr[mi] = *(const f16x8*)(&lA[cur][(wM + mi * 16 + fr) * 32 + kxo]);
#pragma unroll
        for (int ni = 0; ni < 4; ++ni)
            bfr[ni] = *(const f16x8*)(&lB[cur][(wN + ni * 16 + fr) * 32 + kxo]);
#pragma unroll
        for (int mi = 0; mi < 4; ++mi)
#pragma unroll
            for (int ni = 0; ni < 4; ++ni)
                acc[mi][ni] = __builtin_amdgcn_mfma_f32_16x16x32_f16(
                    afr[mi], bfr[ni], acc[mi][ni], 0, 0, 0);
        __syncthreads();   // drains vmcnt(0): next buf staged; reads of cur done
        cur ^= 1;
    }

    float* dst = part + (size_t)blockIdx.z * TOK * HID;
    const int cn = lane & 15;
    const int rq = (lane >> 4) * 4;
#pragma unroll
    for (int mi = 0; mi < 4; ++mi)
#pragma unroll
        for (int r = 0; r < 4; ++r) {
            const int m = m0 + wM + mi * 16 + rq + r;
#pragma unroll
            for (int ni = 0; ni < 4; ++ni) {
                const int n = n0 + wN + ni * 16 + cn;
                dst[(size_t)m * HID + n] = acc[mi][ni][r];
            }
        }
}

// ---------------------------------------------------------------------------
// Small-K GEMM: 1024 thr = 16 waves (4x4), wave 32x32 (2x2 MFMA), 128x128
// tile, gload_lds staging (1 issue/wave/K-step), swizzled-slot LDS, 2-phase
// double-buffered pipeline.
// MODE 1: outH = f16(acc + (bias?bias[n]:0))
// MODE 3: outH = f16(acc + addv + sum_t probs*up_b)
// MODE 4: outF = acc + addv
// MODE 5: dual N=512 GEMM: by<4 -> down=relu(Ah@B^T+bias); by>=4 -> g=A2@B2^T
// ---------------------------------------------------------------------------
template <int MODE>
__global__ __launch_bounds__(1024, 4) void gemm_w32(
    const _Float16* __restrict__ Ah, const _Float16* __restrict__ B,
    int K, int Ncols,
    float* __restrict__ outF, _Float16* __restrict__ outH,
    const float* __restrict__ bias, const float* __restrict__ addv,
    const float* __restrict__ probs, const float* __restrict__ upb,
    const _Float16* __restrict__ A2, const _Float16* __restrict__ B2,
    _Float16* __restrict__ outH2)
{
    __shared__ _Float16 lA[2][4096];
    __shared__ _Float16 lB[2][4096];
    const int tid  = threadIdx.x;
    const int lane = tid & 63;
    const int wave = tid >> 6;
    const int m0   = blockIdx.x * 128;
    int n0, half = 0;
    const _Float16* Ap = Ah;
    const _Float16* Bp = B;
    if constexpr (MODE == 5) {
        half = blockIdx.y >> 2;
        n0 = (blockIdx.y & 3) * 128;
        if (half) { Ap = A2; Bp = B2; }
    } else {
        n0 = blockIdx.y * 128;
    }
    const int wM = (wave & 3) * 32;
    const int wN = (wave >> 2) * 32;

    f32x4 acc[2][2] = {};

    // waves 0-7 stage A rows 16*i8..16*i8+15; waves 8-15 same for B.
    const int i8   = wave & 7;
    const int srow = lane >> 2;
    const int scol = ((lane & 3) ^ ((lane >> 3) & 3)) * 8;
    const _Float16* gsrc = ((wave < 8)
        ? Ap + (size_t)(m0 + i8 * 16 + srow) * K
        : Bp + (size_t)(n0 + i8 * 16 + srow) * K) + scol;
    _Float16* ldst = ((wave < 8) ? &lA[0][0] : &lB[0][0]) + i8 * 512;

    const int fr  = lane & 15;
    const int khr = lane >> 4;
    const int kxo = (khr ^ ((fr >> 1) & 3)) * 8;

    // prologue: stage tile 0 into buf 0
    GLDS16(gsrc, ldst);
    __syncthreads();

    int cur = 0;
    for (int k0 = 0; k0 < K; k0 += 32) {
        if (k0 + 32 < K)                // issue next-tile load FIRST (overlap)
            GLDS16(gsrc + k0 + 32, ldst + (cur ^ 1) * 4096);
        f16x8 afr[2], bfr[2];
#pragma unroll
        for (int mi = 0; mi < 2; ++mi)
            afr[mi] = *(const f16x8*)(&lA[cur][(wM + mi * 16 + fr) * 32 + kxo]);
#pragma unroll
        for (int ni = 0; ni < 2; ++ni)
            bfr[ni] = *(const f16x8*)(&lB[cur][(wN + ni * 16 + fr) * 32 + kxo]);
#pragma unroll
        for (int mi = 0; mi < 2; ++mi)
#pragma unroll
            for (int ni = 0; ni < 2; ++ni)
                acc[mi][ni] = __builtin_amdgcn_mfma_f32_16x16x32_f16(
                    afr[mi], bfr[ni], acc[mi][ni], 0, 0, 0);
        __syncthreads();
        cur ^= 1;
    }

    const int cn = lane & 15;
    const int rq = (lane >> 4) * 4;
#pragma unroll
    for (int mi = 0; mi < 2; ++mi)
#pragma unroll
        for (int r = 0; r < 4; ++r) {
            const int m = m0 + wM + mi * 16 + rq + r;
#pragma unroll
            for (int ni = 0; ni < 2; ++ni) {
                const int n = n0 + wN + ni * 16 + cn;
                const float v = acc[mi][ni][r];
                if constexpr (MODE == 1) {
                    const float bb = bias ? bias[n] : 0.f;
                    outH[(size_t)m * Ncols + n] = (_Float16)(v + bb);
                } else if constexpr (MODE == 3) {
                    const size_t idx = (size_t)m * Ncols + n;
                    float s = v + addv[idx];
#pragma unroll
                    for (int t = 0; t < 8; ++t)
                        s += probs[(size_t)m * 8 + t] * upb[t * 1024 + n];
                    outH[idx] = (_Float16)s;
                } else if constexpr (MODE == 4) {
                    const size_t idx = (size_t)m * Ncols + n;
                    outF[idx] = v + addv[idx];
                } else {  // MODE 5
                    const size_t idx = (size_t)m * 512 + n;
                    if (half == 0) {
                        const float y = v + bias[n];
                        outH[idx] = (_Float16)(y > 0.f ? y : 0.f);
                    } else {
                        outH2[idx] = (_Float16)v;
                    }
                }
            }
        }
}

// ---------------------------------------------------------------------------
// fused split-K reduce + bias + LN: h = sum_z part[z] + dense_b;
// prenorm = h + it; ai = LN(prenorm); emits h_f32, ai(f16), pn(f16)
// ---------------------------------------------------------------------------
__global__ __launch_bounds__(256) void ln_fused(
    const float* __restrict__ part, int sk,
    const float* __restrict__ dbias, const float* __restrict__ it,
    const float* __restrict__ gam, const float* __restrict__ bet,
    float* __restrict__ h_f32, _Float16* __restrict__ ai, _Float16* __restrict__ pn)
{
    const int n = blockIdx.x, tid = threadIdx.x;
    const int lane = tid & 63, wave = tid >> 6;
    const size_t base = (size_t)n * 1024 + tid * 4;
    f32x4 h = *(const f32x4*)(dbias + tid * 4);
    for (int z = 0; z < sk; ++z)
        h += *(const f32x4*)(part + (size_t)z * TOK * HID + base);
    *(f32x4*)(h_f32 + base) = h;
    f32x4 x = h + *(const f32x4*)(it + base);
    float s = x[0] + x[1] + x[2] + x[3];
    float q = x[0] * x[0] + x[1] * x[1] + x[2] * x[2] + x[3] * x[3];
#pragma unroll
    for (int off = 1; off < 64; off <<= 1) {
        s += __shfl_xor(s, off);
        q += __shfl_xor(q, off);
    }
    __shared__ float rs[4], rq[4];
    if (lane == 0) { rs[wave] = s; rq[wave] = q; }
    __syncthreads();
    s = rs[0] + rs[1] + rs[2] + rs[3];
    q = rq[0] + rq[1] + rq[2] + rq[3];
    const float mu = s * (1.f / 1024.f);
    const float var = q * (1.f / 1024.f) - mu * mu;
    const float rstd = rsqrtf(var + 1e-12f);
    f32x4 gv = *(const f32x4*)(gam + tid * 4);
    f32x4 bv = *(const f32x4*)(bet + tid * 4);
    f16x4 av, pv;
#pragma unroll
    for (int j = 0; j < 4; ++j) {
        const float y = (x[j] - mu) * rstd * gv[j] + bv[j];
        av[j] = (_Float16)y;
        pv[j] = (_Float16)x[j];
    }
    *(f16x4*)(ai + base) = av;
    *(f16x4*)(pn + base) = pv;
}

// final LN: out = LN(fuse) where fuse already = input_tensor + fusion
__global__ __launch_bounds__(256) void ln_out(
    const float* __restrict__ fuse, const float* __restrict__ gam,
    const float* __restrict__ bet, float* __restrict__ outp)
{
    const int n = blockIdx.x, tid = threadIdx.x;
    const int lane = tid & 63, wave = tid >> 6;
    const size_t base = (size_t)n * 1024 + tid * 4;
    f32x4 x = *(const f32x4*)(fuse + base);
    float s = x[0] + x[1] + x[2] + x[3];
    float q = x[0] * x[0] + x[1] * x[1] + x[2] * x[2] + x[3] * x[3];
#pragma unroll
    for (int off = 1; off < 64; off <<= 1) {
        s += __shfl_xor(s, off);
        q += __shfl_xor(q, off);
    }
    __shared__ float rs[4], rq[4];
    if (lane == 0) { rs[wave] = s; rq[wave] = q; }
    __syncthreads();
    s = rs[0] + rs[1] + rs[2] + rs[3];
    q = rq[0] + rq[1] + rq[2] + rq[3];
    const float mu = s * (1.f / 1024.f);
    const float var = q * (1.f / 1024.f) - mu * mu;
    const float rstd = rsqrtf(var + 1e-12f);
    f32x4 gv = *(const f32x4*)(gam + tid * 4);
    f32x4 bv = *(const f32x4*)(bet + tid * 4);
    f32x4 y;
#pragma unroll
    for (int j = 0; j < 4; ++j) y[j] = (x[j] - mu) * rstd * gv[j] + bv[j];
    *(f32x4*)(outp + base) = y;
}

// ---------------------------------------------------------------------------
// scores + softmax over T + wdown = probs * down, per token.
// score[t] (up to a t-independent constant that cancels in softmax) =
//   down . g  +  sum_h qk[h]*up_b[t,h]
// ---------------------------------------------------------------------------
__global__ __launch_bounds__(256) void scores_softmax(
    const _Float16* __restrict__ qk, const float* __restrict__ up_b,
    const _Float16* __restrict__ down, const _Float16* __restrict__ g,
    float* __restrict__ probs_out, _Float16* __restrict__ wdown)
{
    const int n = blockIdx.x, tid = threadIdx.x;
    const int lane = tid & 63, wave = tid >> 6;
    const _Float16* qkrow = qk + (size_t)n * 1024;
    float ub[8] = {};
#pragma unroll
    for (int j = 0; j < 4; ++j) {
        const int h = tid + j * 256;
        const float qkv = (float)qkrow[h];
#pragma unroll
        for (int t = 0; t < 8; ++t) ub[t] += qkv * up_b[t * 1024 + h];
    }
#pragma unroll
    for (int off = 1; off < 64; off <<= 1) {
#pragma unroll
        for (int t = 0; t < 8; ++t) ub[t] += __shfl_xor(ub[t], off);
    }
    __shared__ float red[4][9];
    __shared__ float sd[8];
    __shared__ float pl[8];
    if (lane == 0) {
#pragma unroll
        for (int t = 0; t < 8; ++t) red[wave][t] = ub[t];
    }
    const int c0 = tid * 2;
    const size_t dbase = (size_t)n * 512;
    const float d0 = (float)down[dbase + c0];
    const float d1 = (float)down[dbase + c0 + 1];
    float pz = d0 * (float)g[dbase + c0] + d1 * (float)g[dbase + c0 + 1];
#pragma unroll
    for (int off = 1; off < 32; off <<= 1) pz += __shfl_xor(pz, off);
    if ((lane & 31) == 0) sd[wave * 2 + (lane >> 5)] = pz;
    __syncthreads();
    if (tid == 0) {
        float sc[8];
        float mx = -1e30f;
#pragma unroll
        for (int t = 0; t < 8; ++t) {
            sc[t] = sd[t] + red[0][t] + red[1][t] + red[2][t] + red[3][t];
            mx = fmaxf(mx, sc[t]);
        }
        float sum = 0.f;
#pragma unroll
        for (int t = 0; t < 8; ++t) { sc[t] = expf(sc[t] - mx); sum += sc[t]; }
        const float inv = 1.f / sum;
#pragma unroll
        for (int t = 0; t < 8; ++t) pl[t] = sc[t] * inv;
    }
    __syncthreads();
    const float pr = pl[c0 >> 6];
    wdown[dbase + c0]     = (_Float16)(pr * d0);
    wdown[dbase + c0 + 1] = (_Float16)(pr * d1);
    if (tid < 8) probs_out[(size_t)n * 8 + tid] = pl[tid];
}

// ---------------------------------------------------------------------------
// conversions / layout prep
// ---------------------------------------------------------------------------
__device__ inline void cvt_seg(const float* __restrict__ s, _Float16* __restrict__ d,
                               int n4, int gid, int gsz)
{
    for (int i = gid; i < n4; i += gsz) {
        f32x4 v = ((const f32x4*)s)[i];
        f16x4 o;
        o[0] = (_Float16)v[0]; o[1] = (_Float16)v[1];
        o[2] = (_Float16)v[2]; o[3] = (_Float16)v[3];
        ((f16x4*)d)[i] = o;
    }
}

__global__ __launch_bounds__(256) void convert4(
    const float* s0, _Float16* d0, int n0,
    const float* s1, _Float16* d1, int n1,
    const float* s2, _Float16* d2, int n2,
    const float* s3, _Float16* d3, int n3,
    float* bz)   // zero 1024-float accumulator for bfuse
{
    if (blockIdx.x == 0) {
        f32x4 z = {0.f, 0.f, 0.f, 0.f};
        *(f32x4*)(bz + threadIdx.x * 4) = z;
    }
    const int gid = blockIdx.x * 256 + threadIdx.x;
    const int gsz = gridDim.x * 256;
    cvt_seg(s0, d0, n0, gid, gsz);
    cvt_seg(s1, d1, n1, gid, gsz);
    cvt_seg(s2, d2, n2, gid, gsz);
    cvt_seg(s3, d3, n3, gid, gsz);
}

// in [k,h] fp32 -> outp [h,k] f16; optionally rout[h] += sum_k rvec[k]*in[k,h]
__global__ __launch_bounds__(256) void transpose_kw(
    const float* __restrict__ in, _Float16* __restrict__ outp,
    const float* __restrict__ rvec, float* __restrict__ rout)
{
    __shared__ float t[32][33];
    __shared__ float rpart[8][33];
    const int bx = blockIdx.x * 32;   // h
    const int by = blockIdx.y * 32;   // k
    const int tx = threadIdx.x & 31, ty = threadIdx.x >> 5;
#pragma unroll
    for (int j = 0; j < 32; j += 8)
        t[ty + j][tx] = in[(size_t)(by + ty + j) * 1024 + bx + tx];
    __syncthreads();
#pragma unroll
    for (int j = 0; j < 32; j += 8)
        outp[(size_t)(bx + ty + j) * 1024 + by + tx] = (_Float16)t[tx][ty + j];
    if (rvec) {
        float s = 0.f;
#pragma unroll
        for (int j = 0; j < 4; ++j) {
            const int k = ty * 4 + j;
            s += rvec[by + k] * t[k][tx];
        }
        rpart[ty][tx] = s;
        __syncthreads();
        if (ty == 0) {
            float v = rpart[0][tx];
#pragma unroll
            for (int r = 1; r < 8; ++r) v += rpart[r][tx];
            atomicAdd(rout + bx + tx, v);
        }
    }
}

// up_w [t,h,d] -> w_upg[(t*64+d), h]  and  w_upmix[h, t*64+d]   (f16)
__global__ __launch_bounds__(256) void reshape_up(
    const float* __restrict__ up_w, _Float16* __restrict__ upg,
    _Float16* __restrict__ upmix)
{
    const int i = blockIdx.x * 256 + threadIdx.x;
    const int d = i & 63;
    const int h = (i >> 6) & 1023;
    const int t = i >> 16;
    const float v = up_w[i];
    upg[(size_t)(t * 64 + d) * 1024 + h] = (_Float16)v;
    upmix[(size_t)h * 512 + t * 64 + d]  = (_Float16)v;
}

// ---------------------------------------------------------------------------
extern "C" void kernel_launch(void* const* d_in, const int* in_sizes, int n_in,
                              void* d_out, int out_size, void* d_ws, size_t ws_size,
                              hipStream_t stream)
{
    const float* hs      = (const float*)d_in[0];
    const float* it      = (const float*)d_in[1];
    const float* dense_w = (const float*)d_in[2];
    const float* dense_b = (const float*)d_in[3];
    const float* ln_g    = (const float*)d_in[4];
    const float* ln_b    = (const float*)d_in[5];
    const float* down_w  = (const float*)d_in[6];
    const float* down_b  = (const float*)d_in[7];
    const float* up_w    = (const float*)d_in[8];
    const float* up_b    = (const float*)d_in[9];
    const float* key_w   = (const float*)d_in[10];
    const float* key_b   = (const float*)d_in[11];
    const float* query_w = (const float*)d_in[12];
    const float* query_b = (const float*)d_in[13];
    const float* value_w = (const float*)d_in[14];
    float* outp = (float*)d_out;
    (void)in_sizes; (void)n_in; (void)out_size; (void)key_b;

    const size_t MiB = 1ull << 20;
    // persistent region (52 MiB)
    char* p = (char*)d_ws;
    _Float16* w_dense  = (_Float16*)p; p += 8 * MiB;
    _Float16* w_queryT = (_Float16*)p; p += 2 * MiB;   // query_w^T [h,q] f16
    _Float16* w_keyT   = (_Float16*)p; p += 2 * MiB;   // key_w^T [h,k] f16
    _Float16* w_value  = (_Float16*)p; p += 2 * MiB;
    _Float16* w_fuseT  = (_Float16*)p; p += 2 * MiB;   // (Wq^T Wk)^T [h',h] f16
    _Float16* w_down   = (_Float16*)p; p += 1 * MiB;
    _Float16* w_upg    = (_Float16*)p; p += 1 * MiB;
    _Float16* w_upmix  = (_Float16*)p; p += 1 * MiB;
    float*    bfuse    = (float*)p;    p += 1 * MiB;   // qb @ Wk  (1024 f32)
    float*    h_f32    = (float*)p;    p += 16 * MiB;
    _Float16* ai       = (_Float16*)p; p += 8 * MiB;   // reused as `mixed`
    _Float16* pn       = (_Float16*)p; p += 8 * MiB;
    // hs_h (32 MiB) aliases h_f32+ai+pn: dead before ln_fused writes them
    _Float16* hs_h = (_Float16*)h_f32;
    // region B: split-K partials first, then (aliased) activations
    char* rb = p;
    const int sk = (ws_size >= (size_t)(52 + 64) * MiB) ? 4 : 2;
    float*    part  = (float*)rb;                 // sk * 16 MiB
    _Float16* qk    = (_Float16*)(rb +  8 * MiB); // 8 MiB   (part dead by then)
    _Float16* down  = (_Float16*)(rb + 16 * MiB); // 4 MiB
    _Float16* g     = (_Float16*)(rb + 20 * MiB); // 4 MiB
    _Float16* wdown = (_Float16*)(rb + 24 * MiB); // 4 MiB
    float*    probs = (float*)(rb + 28 * MiB);    // 128 KiB
    float*    fuse  = (float*)rb;                 // 16 MiB, aliases qk (dead)
    _Float16* mixed = ai;

    // weight prep + hs fp32->f16; zero bfuse (block 0)
    convert4<<<2048, 256, 0, stream>>>(hs, hs_h, TOK * IDIM / 4,
                                       dense_w, w_dense, HID * IDIM / 4,
                                       value_w, w_value, HID * HID / 4,
                                       down_w,  w_down,  512 * HID / 4,
                                       bfuse);
    // w_keyT = key_w^T, and bfuse[h'] = sum_k query_b[k]*key_w[k,h']
    transpose_kw<<<dim3(32, 32), 256, 0, stream>>>(key_w, w_keyT, query_b, bfuse);
    transpose_kw<<<dim3(32, 32), 256, 0, stream>>>(query_w, w_queryT, nullptr, nullptr);
    reshape_up<<<2048, 256, 0, stream>>>(up_w, w_upg, w_upmix);
    // w_fuseT[h',h] = sum_q key_w[q,h'] * query_w[q,h]   (weight-only GEMM)
    gemm_w32<1><<<dim3(8, 8), 1024, 0, stream>>>(
        w_keyT, w_queryT, HID, HID, nullptr, w_fuseT, nullptr, nullptr, nullptr,
        nullptr, nullptr, nullptr, nullptr);

    // dense partials: part[z] = hs_h @ dense_w^T  (K chunk per z)
    gemm_dense<<<dim3(32, 8, sk), 256, 0, stream>>>(hs_h, w_dense, IDIM, IDIM / sk, part);
    // h = sum partials + dense_b; ai = LN(h + it); pn = f16(h + it)
    ln_fused<<<TOK, 256, 0, stream>>>(part, sk, dense_b, it, ln_g, ln_b, h_f32, ai, pn);
    // qk = pn @ w_fuseT^T + bfuse   (== (pn@Wq^T + qb) @ Wk)
    gemm_w32<1><<<dim3(32, 8), 1024, 0, stream>>>(
        pn, w_fuseT, HID, HID, nullptr, qk, bfuse, nullptr, nullptr, nullptr,
        nullptr, nullptr, nullptr);
    // dual: down = relu(ai @ w_down^T + down_b);  g = qk @ w_upg^T
    gemm_w32<5><<<dim3(32, 8), 1024, 0, stream>>>(
        ai, w_down, HID, 512, nullptr, down, down_b, nullptr, nullptr, nullptr,
        qk, w_upg, g);
    // scores -> softmax over T -> probs, wdown = probs*down
    scores_softmax<<<TOK, 256, 0, stream>>>(qk, up_b, down, g, probs, wdown);
    // mixed = wdown @ up_w^T + probs@up_b + h
    gemm_w32<3><<<dim3(32, 8), 1024, 0, stream>>>(
        wdown, w_upmix, 512, HID, nullptr, mixed, nullptr, h_f32, probs, up_b,
        nullptr, nullptr, nullptr);
    // fuse = mixed @ value_w^T + input_tensor
    gemm_w32<4><<<dim3(32, 8), 1024, 0, stream>>>(
        mixed, w_value, HID, HID, fuse, nullptr, nullptr, it, nullptr, nullptr,
        nullptr, nullptr, nullptr);
    // out = LN(fuse)
    ln_out<<<TOK, 256, 0, stream>>>(fuse, ln_g, ln_b, outp);
}